// Round 2
// baseline (878.293 us; speedup 1.0000x reference)
//
#include <hip/hip_runtime.h>
#include <math.h>

#define B_ 4
#define C_ 512
#define L_ 2048
#define H_ 8
#define D_ 64

// =====================================================================
// proj_gemm: Y[b][co][l] = sum_c W[co][c] * X[b][c][l] + bias[co]
//            (+ resid[b][co][l] if resid != nullptr)
// (B, C, L) layout; W is (C, C) row-major. Tile 128(co) x 64(l), BK=16,
// 256 threads, 8x4 per thread. Register-prefetched staging.
// =====================================================================
#define BM 128
#define BN 64
#define BSS 68   // Bs row stride (pad: 64 -> 68 spreads staging-write banks)
#define BK 16

__global__ __launch_bounds__(256) void proj_gemm(
    const float* __restrict__ W, const float* __restrict__ bias,
    const float* __restrict__ X, float* __restrict__ Y,
    const float* __restrict__ resid)
{
    __shared__ float As[BK][BM];    // [k][co]
    __shared__ float Bs[BK][BSS];   // [k][l]

    const int b   = blockIdx.z;
    const int co0 = blockIdx.y * BM;
    const int l0  = blockIdx.x * BN;
    const float* Xb = X + (size_t)b * C_ * L_;
    float* Yb       = Y + (size_t)b * C_ * L_;
    const float* Rb = resid ? resid + (size_t)b * C_ * L_ : nullptr;

    const int tid = threadIdx.x;
    const int tx  = tid & 15;   // l:  16 * 4 = 64
    const int ty  = tid >> 4;   // co: 16 * 8 = 128

    // staging thread mapping
    const int arow = tid >> 1;          // 0..127 (W row within tile)
    const int akq  = (tid & 1) * 8;     // 0 or 8 (k quad)
    const int bkk  = tid >> 4;          // 0..15  (k row of Bs)
    const int bl4  = (tid & 15) * 4;    // l quad

    float acc[8][4];
    #pragma unroll
    for (int i = 0; i < 8; ++i)
        #pragma unroll
        for (int j = 0; j < 4; ++j) acc[i][j] = 0.f;

    // ---- prologue: prefetch k0 = 0 into registers ----
    float4 w0, w1, bx;
    {
        const float4* wp = reinterpret_cast<const float4*>(
            W + (size_t)(co0 + arow) * C_ + akq);
        w0 = wp[0]; w1 = wp[1];
        bx = *reinterpret_cast<const float4*>(Xb + (size_t)bkk * L_ + l0 + bl4);
    }

    for (int k0 = 0; k0 < C_; k0 += BK) {
        __syncthreads();   // previous compute finished reading As/Bs
        // ---- commit prefetched registers to LDS ----
        As[akq + 0][arow] = w0.x; As[akq + 1][arow] = w0.y;
        As[akq + 2][arow] = w0.z; As[akq + 3][arow] = w0.w;
        As[akq + 4][arow] = w1.x; As[akq + 5][arow] = w1.y;
        As[akq + 6][arow] = w1.z; As[akq + 7][arow] = w1.w;
        *reinterpret_cast<float4*>(&Bs[bkk][bl4]) = bx;
        __syncthreads();
        // ---- issue next step's loads (latency hides under compute) ----
        if (k0 + BK < C_) {
            const int kn = k0 + BK;
            const float4* wp = reinterpret_cast<const float4*>(
                W + (size_t)(co0 + arow) * C_ + kn + akq);
            w0 = wp[0]; w1 = wp[1];
            bx = *reinterpret_cast<const float4*>(
                Xb + (size_t)(kn + bkk) * L_ + l0 + bl4);
        }
        // ---- compute ----
        #pragma unroll
        for (int kk = 0; kk < BK; ++kk) {
            const float4 a0 = *reinterpret_cast<const float4*>(&As[kk][ty * 8]);
            const float4 a1 = *reinterpret_cast<const float4*>(&As[kk][ty * 8 + 4]);
            const float4 b0 = *reinterpret_cast<const float4*>(&Bs[kk][tx * 4]);
            const float a[8]  = {a0.x, a0.y, a0.z, a0.w, a1.x, a1.y, a1.z, a1.w};
            const float bb[4] = {b0.x, b0.y, b0.z, b0.w};
            #pragma unroll
            for (int i = 0; i < 8; ++i)
                #pragma unroll
                for (int j = 0; j < 4; ++j)
                    acc[i][j] = fmaf(a[i], bb[j], acc[i][j]);
        }
    }

    // ---- epilogue: bias (+ residual), vectorized store over l ----
    #pragma unroll
    for (int i = 0; i < 8; ++i) {
        const int co = co0 + ty * 8 + i;
        const float bv = bias[co];
        const size_t off = (size_t)co * L_ + l0 + tx * 4;
        float4 r;
        r.x = acc[i][0] + bv; r.y = acc[i][1] + bv;
        r.z = acc[i][2] + bv; r.w = acc[i][3] + bv;
        if (Rb) {
            const float4 rv = *reinterpret_cast<const float4*>(Rb + off);
            r.x += rv.x; r.y += rv.y; r.z += rv.z; r.w += rv.w;
        }
        *reinterpret_cast<float4*>(Yb + off) = r;
    }
}

// =====================================================================
// Flash attention. Q/K/V/O in (B, C, L) layout (head h = rows h*D..h*D+63).
// Block = one (b, h, 64-query tile); 256 threads. Online softmax over
// 64-key tiles. K/V staging register-prefetched one tile ahead.
// =====================================================================
#define QT 64
#define KT 64
#define RS 68   // LDS row stride: 16B-aligned, spreads bank groups

__global__ __launch_bounds__(256) void attn_kernel(
    const float* __restrict__ Qt, const float* __restrict__ Kt,
    const float* __restrict__ Vt, float* __restrict__ Ot)
{
    __shared__ float Qs[D_][RS];   // [d][q], pre-scaled
    __shared__ float Ks[D_][RS];   // [d][k]
    __shared__ float Vs[KT][RS];   // [k][d]
    __shared__ float Ps[KT][RS];   // [k][q]

    const int q0 = blockIdx.x * QT;
    const int h  = blockIdx.y;
    const int b  = blockIdx.z;
    const float* Qh = Qt + ((size_t)b * C_ + h * D_) * L_;
    const float* Kh = Kt + ((size_t)b * C_ + h * D_) * L_;
    const float* Vh = Vt + ((size_t)b * C_ + h * D_) * L_;
    float* Oh       = Ot + ((size_t)b * C_ + h * D_) * L_;

    const int tid = threadIdx.x;
    const int tx  = tid & 15;
    const int ty  = tid >> 4;

    const float scale = 0.125f;   // 1/sqrt(64)

    // stage Q tile (once), scaled
    #pragma unroll
    for (int p = 0; p < 4; ++p) {
        const int d  = ty + p * 16;
        const int c4 = tx * 4;
        float4 v = *reinterpret_cast<const float4*>(Qh + (size_t)d * L_ + q0 + c4);
        v.x *= scale; v.y *= scale; v.z *= scale; v.w *= scale;
        *reinterpret_cast<float4*>(&Qs[d][c4]) = v;
    }

    float o[4][4];
    #pragma unroll
    for (int i = 0; i < 4; ++i)
        #pragma unroll
        for (int j = 0; j < 4; ++j) o[i][j] = 0.f;
    float m_r[4] = {-INFINITY, -INFINITY, -INFINITY, -INFINITY};
    float l_r[4] = {0.f, 0.f, 0.f, 0.f};

    // ---- prologue: prefetch K/V tile 0 into registers ----
    float4 kr[4], vr[4];
    #pragma unroll
    for (int p = 0; p < 4; ++p) {
        const int d  = ty + p * 16;
        const int c4 = tx * 4;
        kr[p] = *reinterpret_cast<const float4*>(Kh + (size_t)d * L_ + c4);
        vr[p] = *reinterpret_cast<const float4*>(Vh + (size_t)d * L_ + c4);
    }

    for (int k0 = 0; k0 < L_; k0 += KT) {
        __syncthreads();   // previous PV finished reading Ks/Vs/Ps
        // ---- commit prefetched K/V registers to LDS ----
        #pragma unroll
        for (int p = 0; p < 4; ++p) {
            const int d  = ty + p * 16;
            const int c4 = tx * 4;
            *reinterpret_cast<float4*>(&Ks[d][c4]) = kr[p];
            Vs[c4 + 0][d] = vr[p].x; Vs[c4 + 1][d] = vr[p].y;
            Vs[c4 + 2][d] = vr[p].z; Vs[c4 + 3][d] = vr[p].w;
        }
        __syncthreads();
        // ---- issue next tile's loads (hide under S/softmax/PV) ----
        if (k0 + KT < L_) {
            const int kn = k0 + KT;
            #pragma unroll
            for (int p = 0; p < 4; ++p) {
                const int d  = ty + p * 16;
                const int c4 = tx * 4;
                kr[p] = *reinterpret_cast<const float4*>(Kh + (size_t)d * L_ + kn + c4);
                vr[p] = *reinterpret_cast<const float4*>(Vh + (size_t)d * L_ + kn + c4);
            }
        }

        // ---- S = (scaled Q)^T K : s[qi][kj] ----
        float s[4][4];
        #pragma unroll
        for (int i = 0; i < 4; ++i)
            #pragma unroll
            for (int j = 0; j < 4; ++j) s[i][j] = 0.f;
        #pragma unroll 8
        for (int d = 0; d < D_; ++d) {
            const float4 qf = *reinterpret_cast<const float4*>(&Qs[d][ty * 4]);
            const float4 kf = *reinterpret_cast<const float4*>(&Ks[d][tx * 4]);
            const float qa[4] = {qf.x, qf.y, qf.z, qf.w};
            const float ka[4] = {kf.x, kf.y, kf.z, kf.w};
            #pragma unroll
            for (int i = 0; i < 4; ++i)
                #pragma unroll
                for (int j = 0; j < 4; ++j)
                    s[i][j] = fmaf(qa[i], ka[j], s[i][j]);
        }

        // ---- online softmax per q-row (row spread over 16 tx lanes) ----
        #pragma unroll
        for (int qi = 0; qi < 4; ++qi) {
            float rm = fmaxf(fmaxf(s[qi][0], s[qi][1]), fmaxf(s[qi][2], s[qi][3]));
            rm = fmaxf(rm, __shfl_xor(rm, 1));
            rm = fmaxf(rm, __shfl_xor(rm, 2));
            rm = fmaxf(rm, __shfl_xor(rm, 4));
            rm = fmaxf(rm, __shfl_xor(rm, 8));
            const float mn   = fmaxf(m_r[qi], rm);
            const float corr = __expf(m_r[qi] - mn);
            const float p0 = __expf(s[qi][0] - mn);
            const float p1 = __expf(s[qi][1] - mn);
            const float p2 = __expf(s[qi][2] - mn);
            const float p3 = __expf(s[qi][3] - mn);
            float rs = p0 + p1 + p2 + p3;
            rs += __shfl_xor(rs, 1);
            rs += __shfl_xor(rs, 2);
            rs += __shfl_xor(rs, 4);
            rs += __shfl_xor(rs, 8);
            l_r[qi] = l_r[qi] * corr + rs;
            m_r[qi] = mn;
            #pragma unroll
            for (int j = 0; j < 4; ++j) o[qi][j] *= corr;
            Ps[tx * 4 + 0][ty * 4 + qi] = p0;
            Ps[tx * 4 + 1][ty * 4 + qi] = p1;
            Ps[tx * 4 + 2][ty * 4 + qi] = p2;
            Ps[tx * 4 + 3][ty * 4 + qi] = p3;
        }
        __syncthreads();

        // ---- O += P * V : o[qi][dj] ----
        #pragma unroll 8
        for (int k = 0; k < KT; ++k) {
            const float4 pf = *reinterpret_cast<const float4*>(&Ps[k][ty * 4]);
            const float4 vf = *reinterpret_cast<const float4*>(&Vs[k][tx * 4]);
            const float pa[4] = {pf.x, pf.y, pf.z, pf.w};
            const float va[4] = {vf.x, vf.y, vf.z, vf.w};
            #pragma unroll
            for (int i = 0; i < 4; ++i)
                #pragma unroll
                for (int j = 0; j < 4; ++j)
                    o[i][j] = fmaf(pa[i], va[j], o[i][j]);
        }
    }

    // ---- epilogue: normalize and store to (B,C,L) layout ----
    #pragma unroll
    for (int qi = 0; qi < 4; ++qi) {
        const float inv = 1.f / l_r[qi];
        #pragma unroll
        for (int j = 0; j < 4; ++j) o[qi][j] *= inv;
    }
    #pragma unroll
    for (int dj = 0; dj < 4; ++dj) {
        float4 v;
        v.x = o[0][dj]; v.y = o[1][dj]; v.z = o[2][dj]; v.w = o[3][dj];
        *reinterpret_cast<float4*>(Oh + (size_t)(tx * 4 + dj) * L_ + q0 + ty * 4) = v;
    }
}

// =====================================================================
extern "C" void kernel_launch(void* const* d_in, const int* in_sizes, int n_in,
                              void* d_out, int out_size, void* d_ws, size_t ws_size,
                              hipStream_t stream)
{
    const float* x  = (const float*)d_in[0];
    const float* Wq = (const float*)d_in[1];
    const float* bq = (const float*)d_in[2];
    const float* Wk = (const float*)d_in[3];
    const float* bk = (const float*)d_in[4];
    const float* Wv = (const float*)d_in[5];
    const float* bv = (const float*)d_in[6];
    const float* Wo = (const float*)d_in[7];
    const float* bo = (const float*)d_in[8];
    float* out = (float*)d_out;

    float* ws = (float*)d_ws;
    const size_t N = (size_t)B_ * C_ * L_;
    float* Qt = ws + 0 * N;
    float* Kt = ws + 1 * N;
    float* Vt = ws + 2 * N;
    float* Ot = ws + 3 * N;

    const dim3 gp(L_ / BN, C_ / BM, B_);   // 32 x 4 x 4 = 512 blocks
    proj_gemm<<<gp, 256, 0, stream>>>(Wq, bq, x, Qt, nullptr);
    proj_gemm<<<gp, 256, 0, stream>>>(Wk, bk, x, Kt, nullptr);
    proj_gemm<<<gp, 256, 0, stream>>>(Wv, bv, x, Vt, nullptr);

    const dim3 ga(L_ / QT, H_, B_);        // 32 x 8 x 4 = 1024 blocks
    attn_kernel<<<ga, 256, 0, stream>>>(Qt, Kt, Vt, Ot);

    proj_gemm<<<gp, 256, 0, stream>>>(Wo, bo, Ot, out, x);
}

// Round 3
// 262.323 us; speedup vs baseline: 3.3481x; 3.3481x over previous
//
#include <hip/hip_runtime.h>
#include <math.h>

#define B_ 4
#define C_ 512
#define L_ 2048
#define H_ 8
#define D_ 64
#define SCALE 0.125f

typedef __bf16 bf16x8 __attribute__((ext_vector_type(8)));
typedef float f32x4 __attribute__((ext_vector_type(4)));

__device__ __forceinline__ unsigned short f2bf(float f) {
    unsigned u = __float_as_uint(f);
    return (unsigned short)((u + 0x7FFFu + ((u >> 16) & 1u)) >> 16);
}

__device__ __forceinline__ bf16x8 frag_ld(const unsigned short* p) {
    uint4 v = *reinterpret_cast<const uint4*>(p);
    return __builtin_bit_cast(bf16x8, v);
}

// =====================================================================
// transpose_conv: x (B,C,L) f32  ->  xt (B,L,C) bf16
// 64x64 tiles via fp32 LDS, conflict-aware.
// =====================================================================
__global__ __launch_bounds__(256) void transpose_conv(
    const float* __restrict__ x, unsigned short* __restrict__ xt)
{
    __shared__ float T[64][68];
    const int b  = blockIdx.z;
    const int l0 = blockIdx.x * 64;
    const int c0 = blockIdx.y * 64;
    const int t  = threadIdx.x;
    const float* xb = x + (size_t)b * C_ * L_;
    unsigned short* xtb = xt + (size_t)b * L_ * C_;

    #pragma unroll
    for (int p = 0; p < 4; ++p) {
        const int ci = 16 * p + (t >> 4);
        const int l4 = (t & 15) * 4;
        const float4 v = *reinterpret_cast<const float4*>(
            xb + (size_t)(c0 + ci) * L_ + l0 + l4);
        *reinterpret_cast<float4*>(&T[ci][l4]) = v;
    }
    __syncthreads();

    const int lo = t >> 2;
    const int cb = (t & 3) * 16;
    unsigned w[8];
    #pragma unroll
    for (int k = 0; k < 8; ++k) {
        const unsigned short e0 = f2bf(T[cb + 2 * k][lo]);
        const unsigned short e1 = f2bf(T[cb + 2 * k + 1][lo]);
        w[k] = (unsigned)e0 | ((unsigned)e1 << 16);
    }
    unsigned short* dst = xtb + (size_t)(l0 + lo) * C_ + c0 + cb;
    *reinterpret_cast<uint4*>(dst)     = make_uint4(w[0], w[1], w[2], w[3]);
    *reinterpret_cast<uint4*>(dst + 8) = make_uint4(w[4], w[5], w[6], w[7]);
}

// =====================================================================
// wconv: 4x (512x512) f32 weights -> bf16 (layout unchanged: [co][c])
// =====================================================================
__global__ __launch_bounds__(256) void wconv(
    const float* __restrict__ w0, const float* __restrict__ w1,
    const float* __restrict__ w2, const float* __restrict__ w3,
    unsigned short* __restrict__ o0, unsigned short* __restrict__ o1,
    unsigned short* __restrict__ o2, unsigned short* __restrict__ o3)
{
    const int y = blockIdx.y;
    const float* src; unsigned short* dst;
    if      (y == 0) { src = w0; dst = o0; }
    else if (y == 1) { src = w1; dst = o1; }
    else if (y == 2) { src = w2; dst = o2; }
    else             { src = w3; dst = o3; }
    const size_t idx = ((size_t)blockIdx.x * 256 + threadIdx.x) * 4;
    const float4 v = *reinterpret_cast<const float4*>(src + idx);
    const unsigned a = (unsigned)f2bf(v.x) | ((unsigned)f2bf(v.y) << 16);
    const unsigned b = (unsigned)f2bf(v.z) | ((unsigned)f2bf(v.w) << 16);
    *reinterpret_cast<uint2*>(dst + idx) = make_uint2(a, b);
}

// =====================================================================
// gemm_bf16: C[m][n] = sum_c A[m][c] * Bt[n][c]  (K = 512)
// A: [M][512] bf16 row-major, Bt: [N][512] bf16 row-major.
// Epilogue: + bias (axis n if BIAS_N else m), * out_scale,
//           output bf16 [M][N] if OUT_BF16 else f32 [M][N] (+resid).
// Tile 128x128, 4 waves (2x2), 16 MFMA per 32-wide k-step.
// =====================================================================
template<int BIAS_N, int OUT_BF16, int RESID>
__global__ __launch_bounds__(256) void gemm_bf16(
    const unsigned short* __restrict__ A,
    const unsigned short* __restrict__ Bt,
    const float* __restrict__ bias, float out_scale,
    void* __restrict__ OutP, const float* __restrict__ resid,
    int M, int N, size_t aStr, size_t bStr, size_t oStr, size_t rStr)
{
    __shared__ unsigned short As[128][40];
    __shared__ unsigned short Bs[128][40];

    const int bz = blockIdx.z;
    A  += (size_t)bz * aStr;
    Bt += (size_t)bz * bStr;

    const int n0 = blockIdx.x * 128;
    const int m0 = blockIdx.y * 128;
    const int t  = threadIdx.x;
    const int lane = t & 63, wid = t >> 6;
    const int wm = (wid >> 1) * 64, wn = (wid & 1) * 64;
    const int q16 = lane & 15, g = lane >> 4;

    // staging: thread t covers row t>>1, 16-bf16 chunk (t&1)
    const int srow = t >> 1;
    const int scol = (t & 1) * 16;
    const unsigned short* Ap = A  + (size_t)(m0 + srow) * C_ + scol;
    const unsigned short* Bp = Bt + (size_t)(n0 + srow) * C_ + scol;

    f32x4 zero4 = {0.f, 0.f, 0.f, 0.f};
    f32x4 acc[4][4];
    #pragma unroll
    for (int i = 0; i < 4; ++i)
        #pragma unroll
        for (int j = 0; j < 4; ++j) acc[i][j] = zero4;

    uint4 ar0 = *reinterpret_cast<const uint4*>(Ap);
    uint4 ar1 = *reinterpret_cast<const uint4*>(Ap + 8);
    uint4 br0 = *reinterpret_cast<const uint4*>(Bp);
    uint4 br1 = *reinterpret_cast<const uint4*>(Bp + 8);

    for (int k0 = 0; k0 < C_; k0 += 32) {
        __syncthreads();
        *reinterpret_cast<uint4*>(&As[srow][scol])     = ar0;
        *reinterpret_cast<uint4*>(&As[srow][scol + 8]) = ar1;
        *reinterpret_cast<uint4*>(&Bs[srow][scol])     = br0;
        *reinterpret_cast<uint4*>(&Bs[srow][scol + 8]) = br1;
        __syncthreads();
        if (k0 + 32 < C_) {
            ar0 = *reinterpret_cast<const uint4*>(Ap + k0 + 32);
            ar1 = *reinterpret_cast<const uint4*>(Ap + k0 + 40);
            br0 = *reinterpret_cast<const uint4*>(Bp + k0 + 32);
            br1 = *reinterpret_cast<const uint4*>(Bp + k0 + 40);
        }
        bf16x8 af[4], bfr[4];
        #pragma unroll
        for (int i = 0; i < 4; ++i) af[i]  = frag_ld(&As[wm + 16 * i + q16][8 * g]);
        #pragma unroll
        for (int j = 0; j < 4; ++j) bfr[j] = frag_ld(&Bs[wn + 16 * j + q16][8 * g]);
        #pragma unroll
        for (int i = 0; i < 4; ++i)
            #pragma unroll
            for (int j = 0; j < 4; ++j)
                acc[i][j] = __builtin_amdgcn_mfma_f32_16x16x32_bf16(
                    af[i], bfr[j], acc[i][j], 0, 0, 0);
    }

    // epilogue
    #pragma unroll
    for (int j = 0; j < 4; ++j) {
        const int n = n0 + wn + 16 * j + q16;
        const float bn = BIAS_N ? bias[n] : 0.f;
        #pragma unroll
        for (int i = 0; i < 4; ++i) {
            #pragma unroll
            for (int r = 0; r < 4; ++r) {
                const int m = m0 + wm + 16 * i + 4 * g + r;
                float v = acc[i][j][r];
                v += BIAS_N ? bn : bias[m];
                v *= out_scale;
                if (OUT_BF16) {
                    unsigned short* o = (unsigned short*)OutP + (size_t)bz * oStr;
                    o[(size_t)m * N + n] = f2bf(v);
                } else {
                    float* o = (float*)OutP + (size_t)bz * oStr;
                    if (RESID) v += resid[(size_t)bz * rStr + (size_t)m * N + n];
                    o[(size_t)m * N + n] = v;
                }
            }
        }
    }
}

// =====================================================================
// attn_mfma: flash attention, bf16 MFMA.
// Qb/Kb: [B][L][C] bf16 (Q pre-scaled by 1/8). Vb: [B][C][L] bf16.
// Out Ab: [B][L][C] bf16. Block = (b, h, 64 q-rows); 4 waves x 16 q.
// =====================================================================
__global__ __launch_bounds__(256) void attn_mfma(
    const unsigned short* __restrict__ Qb,
    const unsigned short* __restrict__ Kb,
    const unsigned short* __restrict__ Vb,
    unsigned short* __restrict__ Ab)
{
    __shared__ unsigned short Ks[64][72];   // [k][d]
    __shared__ unsigned short Vs[64][72];   // [d][k]
    __shared__ unsigned short Pw[4][16][72]; // wave-private P [q_local][k]

    const int q0 = blockIdx.x * 64;
    const int h  = blockIdx.y;
    const int b  = blockIdx.z;
    const int t  = threadIdx.x, lane = t & 63, wid = t >> 6;
    const int q16 = lane & 15, g = lane >> 4;

    const unsigned short* Qg = Qb + (size_t)b * L_ * C_;
    const unsigned short* Kg = Kb + (size_t)b * L_ * C_;
    const unsigned short* Vg = Vb + ((size_t)b * C_ + h * D_) * L_;
    unsigned short* Ag       = Ab + (size_t)b * L_ * C_;

    // Q fragments (held in registers for whole block)
    bf16x8 qf[2];
    {
        const unsigned short* qp =
            Qg + (size_t)(q0 + 16 * wid + q16) * C_ + h * D_ + 8 * g;
        qf[0] = frag_ld(qp);
        qf[1] = frag_ld(qp + 32);
    }

    f32x4 zero4 = {0.f, 0.f, 0.f, 0.f};
    f32x4 oacc[4];
    #pragma unroll
    for (int n = 0; n < 4; ++n) oacc[n] = zero4;
    float m_r[4] = {-INFINITY, -INFINITY, -INFINITY, -INFINITY};
    float l_r[4] = {0.f, 0.f, 0.f, 0.f};

    // staging map: row sr (0..63), 16-bf16 chunk sc
    const int sr = t >> 2;
    const int sc = (t & 3) * 16;

    uint4 kr0, kr1, vr0, vr1;
    {
        const unsigned short* kp = Kg + (size_t)sr * C_ + h * D_ + sc;
        kr0 = *reinterpret_cast<const uint4*>(kp);
        kr1 = *reinterpret_cast<const uint4*>(kp + 8);
        const unsigned short* vp = Vg + (size_t)sr * L_ + sc;
        vr0 = *reinterpret_cast<const uint4*>(vp);
        vr1 = *reinterpret_cast<const uint4*>(vp + 8);
    }

    for (int kt = 0; kt < 32; ++kt) {
        __syncthreads();
        *reinterpret_cast<uint4*>(&Ks[sr][sc])     = kr0;
        *reinterpret_cast<uint4*>(&Ks[sr][sc + 8]) = kr1;
        *reinterpret_cast<uint4*>(&Vs[sr][sc])     = vr0;
        *reinterpret_cast<uint4*>(&Vs[sr][sc + 8]) = vr1;
        __syncthreads();
        if (kt + 1 < 32) {
            const int kn = (kt + 1) * 64;
            const unsigned short* kp = Kg + (size_t)(kn + sr) * C_ + h * D_ + sc;
            kr0 = *reinterpret_cast<const uint4*>(kp);
            kr1 = *reinterpret_cast<const uint4*>(kp + 8);
            const unsigned short* vp = Vg + (size_t)sr * L_ + kn + sc;
            vr0 = *reinterpret_cast<const uint4*>(vp);
            vr1 = *reinterpret_cast<const uint4*>(vp + 8);
        }

        // ---- S = Q K^T (pre-scaled) ----
        f32x4 sacc[4];
        #pragma unroll
        for (int n = 0; n < 4; ++n) sacc[n] = zero4;
        #pragma unroll
        for (int s = 0; s < 2; ++s) {
            #pragma unroll
            for (int n = 0; n < 4; ++n) {
                bf16x8 kf = frag_ld(&Ks[16 * n + q16][32 * s + 8 * g]);
                sacc[n] = __builtin_amdgcn_mfma_f32_16x16x32_bf16(
                    qf[s], kf, sacc[n], 0, 0, 0);
            }
        }

        // ---- online softmax (q-row = 4*g + r, spread over 16-lane group) ----
        #pragma unroll
        for (int r = 0; r < 4; ++r) {
            float pm = fmaxf(fmaxf(sacc[0][r], sacc[1][r]),
                             fmaxf(sacc[2][r], sacc[3][r]));
            pm = fmaxf(pm, __shfl_xor(pm, 1));
            pm = fmaxf(pm, __shfl_xor(pm, 2));
            pm = fmaxf(pm, __shfl_xor(pm, 4));
            pm = fmaxf(pm, __shfl_xor(pm, 8));
            const float mn   = fmaxf(m_r[r], pm);
            const float corr = __expf(m_r[r] - mn);
            m_r[r] = mn;
            float p[4], rs = 0.f;
            #pragma unroll
            for (int n = 0; n < 4; ++n) { p[n] = __expf(sacc[n][r] - mn); rs += p[n]; }
            rs += __shfl_xor(rs, 1);
            rs += __shfl_xor(rs, 2);
            rs += __shfl_xor(rs, 4);
            rs += __shfl_xor(rs, 8);
            l_r[r] = l_r[r] * corr + rs;
            #pragma unroll
            for (int n = 0; n < 4; ++n) {
                oacc[n][r] = oacc[n][r] * corr;
                Pw[wid][4 * g + r][16 * n + q16] = f2bf(p[n]);
            }
        }

        // ---- O += P V (wave-private P, no barrier needed) ----
        #pragma unroll
        for (int s2 = 0; s2 < 2; ++s2) {
            bf16x8 pf = frag_ld(&Pw[wid][q16][32 * s2 + 8 * g]);
            #pragma unroll
            for (int n = 0; n < 4; ++n) {
                bf16x8 vf = frag_ld(&Vs[16 * n + q16][32 * s2 + 8 * g]);
                oacc[n] = __builtin_amdgcn_mfma_f32_16x16x32_bf16(
                    pf, vf, oacc[n], 0, 0, 0);
            }
        }
    }

    // ---- epilogue: normalize, store bf16 [l][c] ----
    #pragma unroll
    for (int r = 0; r < 4; ++r) {
        const float inv = 1.f / l_r[r];
        const int q = q0 + 16 * wid + 4 * g + r;
        #pragma unroll
        for (int n = 0; n < 4; ++n) {
            Ag[(size_t)q * C_ + h * D_ + 16 * n + q16] = f2bf(oacc[n][r] * inv);
        }
    }
}

// =====================================================================
extern "C" void kernel_launch(void* const* d_in, const int* in_sizes, int n_in,
                              void* d_out, int out_size, void* d_ws, size_t ws_size,
                              hipStream_t stream)
{
    const float* x  = (const float*)d_in[0];
    const float* Wq = (const float*)d_in[1];
    const float* bq = (const float*)d_in[2];
    const float* Wk = (const float*)d_in[3];
    const float* bk = (const float*)d_in[4];
    const float* Wv = (const float*)d_in[5];
    const float* bv = (const float*)d_in[6];
    const float* Wo = (const float*)d_in[7];
    const float* bo = (const float*)d_in[8];
    float* out = (float*)d_out;

    const size_t NB = (size_t)B_ * L_ * C_;   // 4.19M elems
    const size_t NW = (size_t)C_ * C_;        // 262K elems
    unsigned short* ws16 = (unsigned short*)d_ws;
    unsigned short* xt  = ws16;
    unsigned short* qb  = xt  + NB;
    unsigned short* kb  = qb  + NB;
    unsigned short* vb  = kb  + NB;
    unsigned short* att = vb  + NB;
    unsigned short* wqb = att + NB;
    unsigned short* wkb = wqb + NW;
    unsigned short* wvb = wkb + NW;
    unsigned short* wob = wvb + NW;

    transpose_conv<<<dim3(L_ / 64, C_ / 64, B_), 256, 0, stream>>>(x, xt);
    wconv<<<dim3(256, 4), 256, 0, stream>>>(Wq, Wk, Wv, Wo, wqb, wkb, wvb, wob);

    const size_t LC = (size_t)L_ * C_;
    // Q: A=xt (M=l), Bt=Wq (N=co), bias on n, pre-scale by 1/8 -> qb [l][co]
    gemm_bf16<1, 1, 0><<<dim3(4, 16, B_), 256, 0, stream>>>(
        xt, wqb, bq, SCALE, qb, nullptr, L_, C_, LC, 0, LC, 0);
    // K: same, scale 1 -> kb [l][co]
    gemm_bf16<1, 1, 0><<<dim3(4, 16, B_), 256, 0, stream>>>(
        xt, wkb, bk, 1.0f, kb, nullptr, L_, C_, LC, 0, LC, 0);
    // V: A=Wv (M=co), Bt=xt (N=l), bias on m -> vb [co][l]
    gemm_bf16<0, 1, 0><<<dim3(16, 4, B_), 256, 0, stream>>>(
        wvb, xt, bv, 1.0f, vb, nullptr, C_, L_, 0, LC, LC, 0);

    attn_mfma<<<dim3(L_ / 64, H_, B_), 256, 0, stream>>>(qb, kb, vb, att);

    // O: A=Wo (M=co), Bt=att (N=l), bias on m, f32 out + resid x -> (B,C,L)
    gemm_bf16<0, 0, 1><<<dim3(16, 4, B_), 256, 0, stream>>>(
        wob, att, bo, 1.0f, out, x, C_, L_, 0, LC, LC, LC);
}

// Round 4
// 235.790 us; speedup vs baseline: 3.7249x; 1.1125x over previous
//
#include <hip/hip_runtime.h>
#include <math.h>

#define B_ 4
#define C_ 512
#define L_ 2048
#define H_ 8
#define D_ 64
// 0.125 * log2(e): folded into Q so softmax uses exp2 (raw v_exp_f32)
#define QSCALE 0.18033688011112042f
#define DEFER_THR 12.0f

typedef __bf16 bf16x8 __attribute__((ext_vector_type(8)));
typedef float f32x4 __attribute__((ext_vector_type(4)));

__device__ __forceinline__ unsigned short f2bf(float f) {
    unsigned u = __float_as_uint(f);
    return (unsigned short)((u + 0x7FFFu + ((u >> 16) & 1u)) >> 16);
}
__device__ __forceinline__ unsigned pack2(float a, float b) {
    return (unsigned)f2bf(a) | ((unsigned)f2bf(b) << 16);
}
__device__ __forceinline__ bf16x8 frag_ld(const unsigned short* p) {
    uint4 v = *reinterpret_cast<const uint4*>(p);
    return __builtin_bit_cast(bf16x8, v);
}

// =====================================================================
// transpose_conv: x (B,C,L) f32  ->  xt (B,L,C) bf16
// =====================================================================
__global__ __launch_bounds__(256) void transpose_conv(
    const float* __restrict__ x, unsigned short* __restrict__ xt)
{
    __shared__ float T[64][68];
    const int b  = blockIdx.z;
    const int l0 = blockIdx.x * 64;
    const int c0 = blockIdx.y * 64;
    const int t  = threadIdx.x;
    const float* xb = x + (size_t)b * C_ * L_;
    unsigned short* xtb = xt + (size_t)b * L_ * C_;

    #pragma unroll
    for (int p = 0; p < 4; ++p) {
        const int ci = 16 * p + (t >> 4);
        const int l4 = (t & 15) * 4;
        const float4 v = *reinterpret_cast<const float4*>(
            xb + (size_t)(c0 + ci) * L_ + l0 + l4);
        *reinterpret_cast<float4*>(&T[ci][l4]) = v;
    }
    __syncthreads();

    const int lo = t >> 2;
    const int cb = (t & 3) * 16;
    unsigned w[8];
    #pragma unroll
    for (int k = 0; k < 8; ++k)
        w[k] = pack2(T[cb + 2 * k][lo], T[cb + 2 * k + 1][lo]);
    unsigned short* dst = xtb + (size_t)(l0 + lo) * C_ + c0 + cb;
    *reinterpret_cast<uint4*>(dst)     = make_uint4(w[0], w[1], w[2], w[3]);
    *reinterpret_cast<uint4*>(dst + 8) = make_uint4(w[4], w[5], w[6], w[7]);
}

// =====================================================================
// wconv: 4x (512x512) f32 weights -> bf16 (layout unchanged)
// =====================================================================
__global__ __launch_bounds__(256) void wconv(
    const float* __restrict__ w0, const float* __restrict__ w1,
    const float* __restrict__ w2, const float* __restrict__ w3,
    unsigned short* __restrict__ o0, unsigned short* __restrict__ o1,
    unsigned short* __restrict__ o2, unsigned short* __restrict__ o3)
{
    const int y = blockIdx.y;
    const float* src; unsigned short* dst;
    if      (y == 0) { src = w0; dst = o0; }
    else if (y == 1) { src = w1; dst = o1; }
    else if (y == 2) { src = w2; dst = o2; }
    else             { src = w3; dst = o3; }
    const size_t idx = ((size_t)blockIdx.x * 256 + threadIdx.x) * 4;
    const float4 v = *reinterpret_cast<const float4*>(src + idx);
    *reinterpret_cast<uint2*>(dst + idx) =
        make_uint2(pack2(v.x, v.y), pack2(v.z, v.w));
}

// =====================================================================
// qkv_gemm: fused Q/K/V projections, one launch (768 blocks = 3/CU).
// mode 0: qb[l][c] = (xt Wq^T + bq) * QSCALE
// mode 1: kb[l][c] =  xt Wk^T + bk
// mode 2: vb[c][l] =  Wv xt^T + bv   (bias on m)
// Tile 128x128, K=512, 4 waves (2x2).
// =====================================================================
__global__ __launch_bounds__(256) void qkv_gemm(
    const unsigned short* __restrict__ xt,
    const unsigned short* __restrict__ wq, const unsigned short* __restrict__ wk,
    const unsigned short* __restrict__ wv,
    const float* __restrict__ bq, const float* __restrict__ bk,
    const float* __restrict__ bv,
    unsigned short* __restrict__ qb, unsigned short* __restrict__ kb,
    unsigned short* __restrict__ vb)
{
    __shared__ unsigned short As[128][40];
    __shared__ unsigned short Bs[128][40];

    const int mode = blockIdx.z >> 2;
    const int b    = blockIdx.z & 3;
    const size_t LC = (size_t)L_ * C_;

    const unsigned short *A, *Bt;
    const float* bias;
    unsigned short* Out;
    float scale = 1.0f;
    int m0, n0, oN, biasN;
    if (mode == 0) {
        A = xt + (size_t)b * LC; Bt = wq; bias = bq; Out = qb + (size_t)b * LC;
        m0 = blockIdx.y * 128; n0 = blockIdx.x * 128; oN = C_; biasN = 1;
        scale = QSCALE;
    } else if (mode == 1) {
        A = xt + (size_t)b * LC; Bt = wk; bias = bk; Out = kb + (size_t)b * LC;
        m0 = blockIdx.y * 128; n0 = blockIdx.x * 128; oN = C_; biasN = 1;
    } else {
        A = wv; Bt = xt + (size_t)b * LC; bias = bv; Out = vb + (size_t)b * LC;
        m0 = blockIdx.x * 128; n0 = blockIdx.y * 128; oN = L_; biasN = 0;
    }

    const int t = threadIdx.x;
    const int lane = t & 63, wid = t >> 6;
    const int wm = (wid >> 1) * 64, wn = (wid & 1) * 64;
    const int q16 = lane & 15, g = lane >> 4;

    const int srow = t >> 1;
    const int scol = (t & 1) * 16;
    const unsigned short* Ap = A  + (size_t)(m0 + srow) * C_ + scol;
    const unsigned short* Bp = Bt + (size_t)(n0 + srow) * C_ + scol;

    f32x4 zero4 = {0.f, 0.f, 0.f, 0.f};
    f32x4 acc[4][4];
    #pragma unroll
    for (int i = 0; i < 4; ++i)
        #pragma unroll
        for (int j = 0; j < 4; ++j) acc[i][j] = zero4;

    uint4 ar0 = *reinterpret_cast<const uint4*>(Ap);
    uint4 ar1 = *reinterpret_cast<const uint4*>(Ap + 8);
    uint4 br0 = *reinterpret_cast<const uint4*>(Bp);
    uint4 br1 = *reinterpret_cast<const uint4*>(Bp + 8);

    for (int k0 = 0; k0 < C_; k0 += 32) {
        __syncthreads();
        *reinterpret_cast<uint4*>(&As[srow][scol])     = ar0;
        *reinterpret_cast<uint4*>(&As[srow][scol + 8]) = ar1;
        *reinterpret_cast<uint4*>(&Bs[srow][scol])     = br0;
        *reinterpret_cast<uint4*>(&Bs[srow][scol + 8]) = br1;
        __syncthreads();
        if (k0 + 32 < C_) {
            ar0 = *reinterpret_cast<const uint4*>(Ap + k0 + 32);
            ar1 = *reinterpret_cast<const uint4*>(Ap + k0 + 40);
            br0 = *reinterpret_cast<const uint4*>(Bp + k0 + 32);
            br1 = *reinterpret_cast<const uint4*>(Bp + k0 + 40);
        }
        bf16x8 af[4], bfr[4];
        #pragma unroll
        for (int i = 0; i < 4; ++i) af[i]  = frag_ld(&As[wm + 16 * i + q16][8 * g]);
        #pragma unroll
        for (int j = 0; j < 4; ++j) bfr[j] = frag_ld(&Bs[wn + 16 * j + q16][8 * g]);
        #pragma unroll
        for (int i = 0; i < 4; ++i)
            #pragma unroll
            for (int j = 0; j < 4; ++j)
                acc[i][j] = __builtin_amdgcn_mfma_f32_16x16x32_bf16(
                    af[i], bfr[j], acc[i][j], 0, 0, 0);
    }

    #pragma unroll
    for (int j = 0; j < 4; ++j) {
        const int n = n0 + wn + 16 * j + q16;
        const float bn = biasN ? bias[n] : 0.f;
        #pragma unroll
        for (int i = 0; i < 4; ++i) {
            #pragma unroll
            for (int r = 0; r < 4; ++r) {
                const int m = m0 + wm + 16 * i + 4 * g + r;
                float v = acc[i][j][r] + (biasN ? bn : bias[m]);
                Out[(size_t)m * oN + n] = f2bf(v * scale);
            }
        }
    }
}

// =====================================================================
// gemm_out: out(B,C,L) f32 = Wo @ att^T + bo + x   (A=Wo[co][c], Bt=att[l][c])
// =====================================================================
__global__ __launch_bounds__(256) void gemm_out(
    const unsigned short* __restrict__ A,
    const unsigned short* __restrict__ Bt,
    const float* __restrict__ bias,
    float* __restrict__ Out, const float* __restrict__ resid)
{
    __shared__ unsigned short As[128][40];
    __shared__ unsigned short Bs[128][40];

    const int bz = blockIdx.z;
    const size_t LC = (size_t)L_ * C_;
    Bt    += (size_t)bz * LC;
    Out   += (size_t)bz * LC;
    resid += (size_t)bz * LC;

    const int n0 = blockIdx.x * 128;   // l
    const int m0 = blockIdx.y * 128;   // co
    const int t  = threadIdx.x;
    const int lane = t & 63, wid = t >> 6;
    const int wm = (wid >> 1) * 64, wn = (wid & 1) * 64;
    const int q16 = lane & 15, g = lane >> 4;

    const int srow = t >> 1;
    const int scol = (t & 1) * 16;
    const unsigned short* Ap = A  + (size_t)(m0 + srow) * C_ + scol;
    const unsigned short* Bp = Bt + (size_t)(n0 + srow) * C_ + scol;

    f32x4 zero4 = {0.f, 0.f, 0.f, 0.f};
    f32x4 acc[4][4];
    #pragma unroll
    for (int i = 0; i < 4; ++i)
        #pragma unroll
        for (int j = 0; j < 4; ++j) acc[i][j] = zero4;

    uint4 ar0 = *reinterpret_cast<const uint4*>(Ap);
    uint4 ar1 = *reinterpret_cast<const uint4*>(Ap + 8);
    uint4 br0 = *reinterpret_cast<const uint4*>(Bp);
    uint4 br1 = *reinterpret_cast<const uint4*>(Bp + 8);

    for (int k0 = 0; k0 < C_; k0 += 32) {
        __syncthreads();
        *reinterpret_cast<uint4*>(&As[srow][scol])     = ar0;
        *reinterpret_cast<uint4*>(&As[srow][scol + 8]) = ar1;
        *reinterpret_cast<uint4*>(&Bs[srow][scol])     = br0;
        *reinterpret_cast<uint4*>(&Bs[srow][scol + 8]) = br1;
        __syncthreads();
        if (k0 + 32 < C_) {
            ar0 = *reinterpret_cast<const uint4*>(Ap + k0 + 32);
            ar1 = *reinterpret_cast<const uint4*>(Ap + k0 + 40);
            br0 = *reinterpret_cast<const uint4*>(Bp + k0 + 32);
            br1 = *reinterpret_cast<const uint4*>(Bp + k0 + 40);
        }
        bf16x8 af[4], bfr[4];
        #pragma unroll
        for (int i = 0; i < 4; ++i) af[i]  = frag_ld(&As[wm + 16 * i + q16][8 * g]);
        #pragma unroll
        for (int j = 0; j < 4; ++j) bfr[j] = frag_ld(&Bs[wn + 16 * j + q16][8 * g]);
        #pragma unroll
        for (int i = 0; i < 4; ++i)
            #pragma unroll
            for (int j = 0; j < 4; ++j)
                acc[i][j] = __builtin_amdgcn_mfma_f32_16x16x32_bf16(
                    af[i], bfr[j], acc[i][j], 0, 0, 0);
    }

    #pragma unroll
    for (int j = 0; j < 4; ++j) {
        const int n = n0 + wn + 16 * j + q16;
        #pragma unroll
        for (int i = 0; i < 4; ++i) {
            #pragma unroll
            for (int r = 0; r < 4; ++r) {
                const int m = m0 + wm + 16 * i + 4 * g + r;
                const size_t off = (size_t)m * L_ + n;
                Out[off] = acc[i][j][r] + bias[m] + resid[off];
            }
        }
    }
}

// =====================================================================
// attn_mfma: flash attention, swapped QK^T + in-register softmax (exp2)
// Qb/Kb: [B][L][C] bf16 (Q pre-scaled by QSCALE). Vb: [B][C][L] bf16.
// Out Ab: [B][L][C] bf16. Block = (b,h,64 q); 4 waves x 16 q.
// =====================================================================
__global__ __launch_bounds__(256) void attn_mfma(
    const unsigned short* __restrict__ Qb,
    const unsigned short* __restrict__ Kb,
    const unsigned short* __restrict__ Vb,
    unsigned short* __restrict__ Ab)
{
    __shared__ unsigned short Ks[64][72];    // [k][d]
    __shared__ unsigned short Vs[64][72];    // [d][k]
    __shared__ unsigned short Pw[4][16][72]; // wave-private P [q][k]

    const int q0 = blockIdx.x * 64;
    const int h  = blockIdx.y;
    const int b  = blockIdx.z;
    const int t  = threadIdx.x, lane = t & 63, wid = t >> 6;
    const int q16 = lane & 15, g = lane >> 4;

    const unsigned short* Qg = Qb + (size_t)b * L_ * C_;
    const unsigned short* Kg = Kb + (size_t)b * L_ * C_;
    const unsigned short* Vg = Vb + ((size_t)b * C_ + h * D_) * L_;
    unsigned short* Ag       = Ab + (size_t)b * L_ * C_;

    // Q fragments (B-operand of swapped QK^T): lane&15 = q row
    bf16x8 qf[2];
    {
        const unsigned short* qp =
            Qg + (size_t)(q0 + 16 * wid + q16) * C_ + h * D_ + 8 * g;
        qf[0] = frag_ld(qp);
        qf[1] = frag_ld(qp + 32);
    }

    f32x4 zero4 = {0.f, 0.f, 0.f, 0.f};
    f32x4 oacc[4];
    #pragma unroll
    for (int n = 0; n < 4; ++n) oacc[n] = zero4;
    float m_s = -INFINITY;   // softmax state for row q16 (exp2 domain)
    float l_s = 0.f;

    const int sr = t >> 2;
    const int sc = (t & 3) * 16;

    uint4 kr0, kr1, vr0, vr1;
    {
        const unsigned short* kp = Kg + (size_t)sr * C_ + h * D_ + sc;
        kr0 = *reinterpret_cast<const uint4*>(kp);
        kr1 = *reinterpret_cast<const uint4*>(kp + 8);
        const unsigned short* vp = Vg + (size_t)sr * L_ + sc;
        vr0 = *reinterpret_cast<const uint4*>(vp);
        vr1 = *reinterpret_cast<const uint4*>(vp + 8);
    }

    for (int kt = 0; kt < 32; ++kt) {
        __syncthreads();
        *reinterpret_cast<uint4*>(&Ks[sr][sc])     = kr0;
        *reinterpret_cast<uint4*>(&Ks[sr][sc + 8]) = kr1;
        *reinterpret_cast<uint4*>(&Vs[sr][sc])     = vr0;
        *reinterpret_cast<uint4*>(&Vs[sr][sc + 8]) = vr1;
        __syncthreads();
        if (kt + 1 < 32) {
            const int kn = (kt + 1) * 64;
            const unsigned short* kp = Kg + (size_t)(kn + sr) * C_ + h * D_ + sc;
            kr0 = *reinterpret_cast<const uint4*>(kp);
            kr1 = *reinterpret_cast<const uint4*>(kp + 8);
            const unsigned short* vp = Vg + (size_t)sr * L_ + kn + sc;
            vr0 = *reinterpret_cast<const uint4*>(vp);
            vr1 = *reinterpret_cast<const uint4*>(vp + 8);
        }

        // ---- S^T = K Q^T : sacc[f][r] = S[k=16f+4g+r][q=q16] ----
        f32x4 sacc[4];
        #pragma unroll
        for (int f = 0; f < 4; ++f) sacc[f] = zero4;
        #pragma unroll
        for (int s = 0; s < 2; ++s) {
            #pragma unroll
            for (int f = 0; f < 4; ++f) {
                bf16x8 kf = frag_ld(&Ks[16 * f + q16][32 * s + 8 * g]);
                sacc[f] = __builtin_amdgcn_mfma_f32_16x16x32_bf16(
                    kf, qf[s], sacc[f], 0, 0, 0);
            }
        }

        // ---- in-register online softmax (row = q16), exp2 domain ----
        float fm[4];
        #pragma unroll
        for (int f = 0; f < 4; ++f)
            fm[f] = fmaxf(fmaxf(sacc[f][0], sacc[f][1]),
                          fmaxf(sacc[f][2], sacc[f][3]));
        float pm = fmaxf(fmaxf(fm[0], fm[1]), fmaxf(fm[2], fm[3]));
        pm = fmaxf(pm, __shfl_xor(pm, 16));
        pm = fmaxf(pm, __shfl_xor(pm, 32));

        if (!__all(pm - m_s <= DEFER_THR)) {
            const float mn   = fmaxf(m_s, pm);
            const float corr = exp2f(m_s - mn);
            m_s = mn;
            l_s *= corr;
            #pragma unroll
            for (int r = 0; r < 4; ++r) {
                const float c_o = __shfl(corr, 20 * g + r);
                #pragma unroll
                for (int n = 0; n < 4; ++n) oacc[n][r] *= c_o;
            }
        }

        float p[4][4];
        float fs[4];
        #pragma unroll
        for (int f = 0; f < 4; ++f) {
            #pragma unroll
            for (int r = 0; r < 4; ++r) p[f][r] = exp2f(sacc[f][r] - m_s);
            fs[f] = (p[f][0] + p[f][1]) + (p[f][2] + p[f][3]);
        }
        float rs = (fs[0] + fs[1]) + (fs[2] + fs[3]);
        rs += __shfl_xor(rs, 16);
        rs += __shfl_xor(rs, 32);
        l_s += rs;

        // ---- store P (transposed to [q][k], u32 pair-packed) ----
        unsigned* pw = reinterpret_cast<unsigned*>(&Pw[wid][q16][0]);
        #pragma unroll
        for (int f = 0; f < 4; ++f) {
            pw[8 * f + 2 * g]     = pack2(p[f][0], p[f][1]);
            pw[8 * f + 2 * g + 1] = pack2(p[f][2], p[f][3]);
        }

        // ---- O += P V (wave-private P, no barrier) ----
        #pragma unroll
        for (int s2 = 0; s2 < 2; ++s2) {
            bf16x8 pf = frag_ld(&Pw[wid][q16][32 * s2 + 8 * g]);
            #pragma unroll
            for (int n = 0; n < 4; ++n) {
                bf16x8 vf = frag_ld(&Vs[16 * n + q16][32 * s2 + 8 * g]);
                oacc[n] = __builtin_amdgcn_mfma_f32_16x16x32_bf16(
                    pf, vf, oacc[n], 0, 0, 0);
            }
        }
    }

    // ---- epilogue: fetch l for own oacc rows, normalize, store ----
    #pragma unroll
    for (int r = 0; r < 4; ++r) {
        const float l_o = __shfl(l_s, 20 * g + r);
        const float inv = 1.f / l_o;
        const int q = q0 + 16 * wid + 4 * g + r;
        #pragma unroll
        for (int n = 0; n < 4; ++n)
            Ag[(size_t)q * C_ + h * D_ + 16 * n + q16] = f2bf(oacc[n][r] * inv);
    }
}

// =====================================================================
extern "C" void kernel_launch(void* const* d_in, const int* in_sizes, int n_in,
                              void* d_out, int out_size, void* d_ws, size_t ws_size,
                              hipStream_t stream)
{
    const float* x  = (const float*)d_in[0];
    const float* Wq = (const float*)d_in[1];
    const float* bq = (const float*)d_in[2];
    const float* Wk = (const float*)d_in[3];
    const float* bk = (const float*)d_in[4];
    const float* Wv = (const float*)d_in[5];
    const float* bv = (const float*)d_in[6];
    const float* Wo = (const float*)d_in[7];
    const float* bo = (const float*)d_in[8];
    float* out = (float*)d_out;

    const size_t NB = (size_t)B_ * L_ * C_;
    const size_t NW = (size_t)C_ * C_;
    unsigned short* ws16 = (unsigned short*)d_ws;
    unsigned short* xt  = ws16;
    unsigned short* qb  = xt  + NB;
    unsigned short* kb  = qb  + NB;
    unsigned short* vb  = kb  + NB;
    unsigned short* att = vb  + NB;
    unsigned short* wqb = att + NB;
    unsigned short* wkb = wqb + NW;
    unsigned short* wvb = wkb + NW;
    unsigned short* wob = wvb + NW;

    transpose_conv<<<dim3(L_ / 64, C_ / 64, B_), 256, 0, stream>>>(x, xt);
    wconv<<<dim3(256, 4), 256, 0, stream>>>(Wq, Wk, Wv, Wo, wqb, wkb, wvb, wob);

    qkv_gemm<<<dim3(4, 16, 3 * B_), 256, 0, stream>>>(
        xt, wqb, wkb, wvb, bq, bk, bv, qb, kb, vb);

    attn_mfma<<<dim3(L_ / 64, H_, B_), 256, 0, stream>>>(qb, kb, vb, att);

    gemm_out<<<dim3(16, 4, B_), 256, 0, stream>>>(wob, att, bo, out, x);
}

// Round 5
// 211.139 us; speedup vs baseline: 4.1598x; 1.1167x over previous
//
#include <hip/hip_runtime.h>
#include <math.h>

#define B_ 4
#define C_ 512
#define L_ 2048
#define H_ 8
#define D_ 64
// 0.125 * log2(e): folded into Q so softmax uses exp2 (raw v_exp_f32)
#define QSCALE 0.18033688011112042f
#define DEFER_THR 12.0f

typedef __bf16 bf16x8 __attribute__((ext_vector_type(8)));
typedef float f32x4 __attribute__((ext_vector_type(4)));

__device__ __forceinline__ unsigned cvt_pk(float lo, float hi) {
    unsigned r;
    asm("v_cvt_pk_bf16_f32 %0, %1, %2" : "=v"(r) : "v"(lo), "v"(hi));
    return r;
}
__device__ __forceinline__ unsigned short f2bf_hw(float a) {
    unsigned r;
    asm("v_cvt_pk_bf16_f32 %0, %1, %1" : "=v"(r) : "v"(a));
    return (unsigned short)r;
}
__device__ __forceinline__ bf16x8 frag_ld(const unsigned short* p) {
    uint4 v = *reinterpret_cast<const uint4*>(p);
    return __builtin_bit_cast(bf16x8, v);
}
__device__ __forceinline__ float fmax3(float a, float b, float c) {
    return fmaxf(fmaxf(a, b), c);   // clang fuses to v_max3_f32
}
// async global->LDS, 16B per lane; LDS dest = wave-uniform base + lane*16
__device__ __forceinline__ void glds16(const void* g, void* l) {
    __builtin_amdgcn_global_load_lds(
        (const __attribute__((address_space(1))) void*)g,
        (__attribute__((address_space(3))) void*)l, 16, 0, 0);
}

// =====================================================================
// prep: z<4  -> transpose x (B,C,L) f32 -> xt (B,L,C) bf16 (64x64 tiles)
//       z>=4 -> convert weight matrix (z-4) f32 -> bf16
// =====================================================================
__global__ __launch_bounds__(256) void prep(
    const float* __restrict__ x,
    const float* __restrict__ w0, const float* __restrict__ w1,
    const float* __restrict__ w2, const float* __restrict__ w3,
    unsigned short* __restrict__ xt,
    unsigned short* __restrict__ o0, unsigned short* __restrict__ o1,
    unsigned short* __restrict__ o2, unsigned short* __restrict__ o3)
{
    __shared__ float T[64][68];
    const int t = threadIdx.x;

    if (blockIdx.z < B_) {
        const int b  = blockIdx.z;
        const int l0 = blockIdx.x * 64;
        const int c0 = blockIdx.y * 64;
        const float* xb = x + (size_t)b * C_ * L_;
        unsigned short* xtb = xt + (size_t)b * L_ * C_;

        #pragma unroll
        for (int p = 0; p < 4; ++p) {
            const int ci = 16 * p + (t >> 4);
            const int l4 = (t & 15) * 4;
            *reinterpret_cast<float4*>(&T[ci][l4]) =
                *reinterpret_cast<const float4*>(xb + (size_t)(c0 + ci) * L_ + l0 + l4);
        }
        __syncthreads();

        const int lo = t >> 2;
        const int cb = (t & 3) * 16;
        unsigned w[8];
        #pragma unroll
        for (int k = 0; k < 8; ++k)
            w[k] = cvt_pk(T[cb + 2 * k][lo], T[cb + 2 * k + 1][lo]);
        unsigned short* dst = xtb + (size_t)(l0 + lo) * C_ + c0 + cb;
        *reinterpret_cast<uint4*>(dst)     = make_uint4(w[0], w[1], w[2], w[3]);
        *reinterpret_cast<uint4*>(dst + 8) = make_uint4(w[4], w[5], w[6], w[7]);
    } else {
        const int m = blockIdx.z - B_;
        const float* src; unsigned short* dst;
        if      (m == 0) { src = w0; dst = o0; }
        else if (m == 1) { src = w1; dst = o1; }
        else if (m == 2) { src = w2; dst = o2; }
        else             { src = w3; dst = o3; }
        const int flat = blockIdx.x + 32 * blockIdx.y;   // 0..255
        const size_t idx = ((size_t)flat * 256 + t) * 4;
        const float4 v = *reinterpret_cast<const float4*>(src + idx);
        *reinterpret_cast<uint2*>(dst + idx) =
            make_uint2(cvt_pk(v.x, v.y), cvt_pk(v.z, v.w));
    }
}

// =====================================================================
// qkv_gemm: fused Q/K/V projections (global_load_lds staging, m97-style).
// mode 0: qb[l][c] = (xt Wq^T + bq) * QSCALE
// mode 1: kb[l][c] =  xt Wk^T + bk
// mode 2: vb[c][l] =  Wv xt^T + bv   (bias on m)
// Tile 128x128, BK=32, 4 waves (2x2). grid (4,16,12) = 768 blocks.
// =====================================================================
__global__ __launch_bounds__(256) void qkv_gemm(
    const unsigned short* __restrict__ xt,
    const unsigned short* __restrict__ wq, const unsigned short* __restrict__ wk,
    const unsigned short* __restrict__ wv,
    const float* __restrict__ bq, const float* __restrict__ bk,
    const float* __restrict__ bv,
    unsigned short* __restrict__ qb, unsigned short* __restrict__ kb,
    unsigned short* __restrict__ vb)
{
    __shared__ unsigned short As[128][32];
    __shared__ unsigned short Bs[128][32];

    const int mode = blockIdx.z >> 2;
    const int b    = blockIdx.z & 3;
    const size_t LC = (size_t)L_ * C_;

    const unsigned short *A, *Bt;
    const float* bias;
    unsigned short* Out;
    float scale = 1.0f;
    int m0, n0, oN, biasN;
    if (mode == 0) {
        A = xt + (size_t)b * LC; Bt = wq; bias = bq; Out = qb + (size_t)b * LC;
        m0 = blockIdx.y * 128; n0 = blockIdx.x * 128; oN = C_; biasN = 1;
        scale = QSCALE;
    } else if (mode == 1) {
        A = xt + (size_t)b * LC; Bt = wk; bias = bk; Out = kb + (size_t)b * LC;
        m0 = blockIdx.y * 128; n0 = blockIdx.x * 128; oN = C_; biasN = 1;
    } else {
        A = wv; Bt = xt + (size_t)b * LC; bias = bv; Out = vb + (size_t)b * LC;
        m0 = blockIdx.x * 128; n0 = blockIdx.y * 128; oN = L_; biasN = 0;
    }

    const int t = threadIdx.x;
    const int lane = t & 63, wid = t >> 6;
    const int wm = (wid >> 1) * 64, wn = (wid & 1) * 64;
    const int q16 = lane & 15, g = lane >> 4;

    // glds staging: wave wid covers rows [wid*32, wid*32+32), 2 calls/operand
    const int gr = wid * 32 + (lane >> 2);
    const int gc = (lane & 3) * 8;
    const unsigned short* Ap0 = A  + (size_t)(m0 + gr) * C_ + gc;
    const unsigned short* Ap1 = Ap0 + 16 * C_;
    const unsigned short* Bp0 = Bt + (size_t)(n0 + gr) * C_ + gc;
    const unsigned short* Bp1 = Bp0 + 16 * C_;
    unsigned short* lA0 = &As[wid * 32][0];
    unsigned short* lA1 = &As[wid * 32 + 16][0];
    unsigned short* lB0 = &Bs[wid * 32][0];
    unsigned short* lB1 = &Bs[wid * 32 + 16][0];

    f32x4 zero4 = {0.f, 0.f, 0.f, 0.f};
    f32x4 acc[4][4];
    #pragma unroll
    for (int i = 0; i < 4; ++i)
        #pragma unroll
        for (int j = 0; j < 4; ++j) acc[i][j] = zero4;

    for (int k0 = 0; k0 < C_; k0 += 32) {
        __syncthreads();                       // prev tile reads done
        glds16(Ap0 + k0, lA0); glds16(Ap1 + k0, lA1);
        glds16(Bp0 + k0, lB0); glds16(Bp1 + k0, lB1);
        __syncthreads();                       // vmcnt(0) drained before barrier
        bf16x8 af[4], bfr[4];
        #pragma unroll
        for (int i = 0; i < 4; ++i) af[i]  = frag_ld(&As[wm + 16 * i + q16][8 * g]);
        #pragma unroll
        for (int j = 0; j < 4; ++j) bfr[j] = frag_ld(&Bs[wn + 16 * j + q16][8 * g]);
        #pragma unroll
        for (int i = 0; i < 4; ++i)
            #pragma unroll
            for (int j = 0; j < 4; ++j)
                acc[i][j] = __builtin_amdgcn_mfma_f32_16x16x32_bf16(
                    af[i], bfr[j], acc[i][j], 0, 0, 0);
    }

    #pragma unroll
    for (int j = 0; j < 4; ++j) {
        const int n = n0 + wn + 16 * j + q16;
        const float bn = biasN ? bias[n] : 0.f;
        #pragma unroll
        for (int i = 0; i < 4; ++i) {
            #pragma unroll
            for (int r = 0; r < 4; ++r) {
                const int m = m0 + wm + 16 * i + 4 * g + r;
                const float v = acc[i][j][r] + (biasN ? bn : bias[m]);
                Out[(size_t)m * oN + n] = f2bf_hw(v * scale);
            }
        }
    }
}

// =====================================================================
// gemm_out: out(B,C,L) f32 = Wo @ att^T + bo + x  (reg-prefetch staging;
// 1 block/CU so in-block prefetch hides latency better than glds here)
// =====================================================================
__global__ __launch_bounds__(256) void gemm_out(
    const unsigned short* __restrict__ A,
    const unsigned short* __restrict__ Bt,
    const float* __restrict__ bias,
    float* __restrict__ Out, const float* __restrict__ resid)
{
    __shared__ unsigned short As[128][40];
    __shared__ unsigned short Bs[128][40];

    const int bz = blockIdx.z;
    const size_t LC = (size_t)L_ * C_;
    Bt    += (size_t)bz * LC;
    Out   += (size_t)bz * LC;
    resid += (size_t)bz * LC;

    const int n0 = blockIdx.x * 128;   // l
    const int m0 = blockIdx.y * 128;   // co
    const int t  = threadIdx.x;
    const int lane = t & 63, wid = t >> 6;
    const int wm = (wid >> 1) * 64, wn = (wid & 1) * 64;
    const int q16 = lane & 15, g = lane >> 4;

    const int srow = t >> 1;
    const int scol = (t & 1) * 16;
    const unsigned short* Ap = A  + (size_t)(m0 + srow) * C_ + scol;
    const unsigned short* Bp = Bt + (size_t)(n0 + srow) * C_ + scol;

    f32x4 zero4 = {0.f, 0.f, 0.f, 0.f};
    f32x4 acc[4][4];
    #pragma unroll
    for (int i = 0; i < 4; ++i)
        #pragma unroll
        for (int j = 0; j < 4; ++j) acc[i][j] = zero4;

    uint4 ar0 = *reinterpret_cast<const uint4*>(Ap);
    uint4 ar1 = *reinterpret_cast<const uint4*>(Ap + 8);
    uint4 br0 = *reinterpret_cast<const uint4*>(Bp);
    uint4 br1 = *reinterpret_cast<const uint4*>(Bp + 8);

    for (int k0 = 0; k0 < C_; k0 += 32) {
        __syncthreads();
        *reinterpret_cast<uint4*>(&As[srow][scol])     = ar0;
        *reinterpret_cast<uint4*>(&As[srow][scol + 8]) = ar1;
        *reinterpret_cast<uint4*>(&Bs[srow][scol])     = br0;
        *reinterpret_cast<uint4*>(&Bs[srow][scol + 8]) = br1;
        __syncthreads();
        if (k0 + 32 < C_) {
            ar0 = *reinterpret_cast<const uint4*>(Ap + k0 + 32);
            ar1 = *reinterpret_cast<const uint4*>(Ap + k0 + 40);
            br0 = *reinterpret_cast<const uint4*>(Bp + k0 + 32);
            br1 = *reinterpret_cast<const uint4*>(Bp + k0 + 40);
        }
        bf16x8 af[4], bfr[4];
        #pragma unroll
        for (int i = 0; i < 4; ++i) af[i]  = frag_ld(&As[wm + 16 * i + q16][8 * g]);
        #pragma unroll
        for (int j = 0; j < 4; ++j) bfr[j] = frag_ld(&Bs[wn + 16 * j + q16][8 * g]);
        #pragma unroll
        for (int i = 0; i < 4; ++i)
            #pragma unroll
            for (int j = 0; j < 4; ++j)
                acc[i][j] = __builtin_amdgcn_mfma_f32_16x16x32_bf16(
                    af[i], bfr[j], acc[i][j], 0, 0, 0);
    }

    #pragma unroll
    for (int j = 0; j < 4; ++j) {
        const int n = n0 + wn + 16 * j + q16;
        #pragma unroll
        for (int i = 0; i < 4; ++i) {
            #pragma unroll
            for (int r = 0; r < 4; ++r) {
                const int m = m0 + wm + 16 * i + 4 * g + r;
                const size_t off = (size_t)m * L_ + n;
                Out[off] = acc[i][j][r] + bias[m] + resid[off];
            }
        }
    }
}

// =====================================================================
// attn_mfma: flash attention, swapped QK^T, in-register softmax (exp2),
// hw cvt_pk P-pack, XOR-swizzled wave-private P, deferred l-reduction.
// =====================================================================
__global__ __launch_bounds__(256) void attn_mfma(
    const unsigned short* __restrict__ Qb,
    const unsigned short* __restrict__ Kb,
    const unsigned short* __restrict__ Vb,
    unsigned short* __restrict__ Ab)
{
    __shared__ unsigned short Ks[64][72];   // [k][d]
    __shared__ unsigned short Vs[64][72];   // [d][k]
    __shared__ unsigned short Pw[4][16][64]; // wave-private P, XOR-swizzled

    const int q0 = blockIdx.x * 64;
    const int h  = blockIdx.y;
    const int b  = blockIdx.z;
    const int t  = threadIdx.x, lane = t & 63, wid = t >> 6;
    const int q16 = lane & 15, g = lane >> 4;
    const int h4 = (q16 & 7) << 2;           // word-index XOR swizzle

    const unsigned short* Qg = Qb + (size_t)b * L_ * C_;
    const unsigned short* Kg = Kb + (size_t)b * L_ * C_;
    const unsigned short* Vg = Vb + ((size_t)b * C_ + h * D_) * L_;
    unsigned short* Ag       = Ab + (size_t)b * L_ * C_;

    unsigned* pw = reinterpret_cast<unsigned*>(&Pw[wid][q16][0]);

    bf16x8 qf[2];
    {
        const unsigned short* qp =
            Qg + (size_t)(q0 + 16 * wid + q16) * C_ + h * D_ + 8 * g;
        qf[0] = frag_ld(qp);
        qf[1] = frag_ld(qp + 32);
    }

    f32x4 zero4 = {0.f, 0.f, 0.f, 0.f};
    f32x4 oacc[4];
    #pragma unroll
    for (int n = 0; n < 4; ++n) oacc[n] = zero4;
    float m_s = -INFINITY;   // running max for q-row q16 (exp2 domain)
    float l_p = 0.f;         // PER-LANE partial sum (reduced at epilogue)

    const int sr = t >> 2;
    const int sc = (t & 3) * 16;

    uint4 kr0, kr1, vr0, vr1;
    {
        const unsigned short* kp = Kg + (size_t)sr * C_ + h * D_ + sc;
        kr0 = *reinterpret_cast<const uint4*>(kp);
        kr1 = *reinterpret_cast<const uint4*>(kp + 8);
        const unsigned short* vp = Vg + (size_t)sr * L_ + sc;
        vr0 = *reinterpret_cast<const uint4*>(vp);
        vr1 = *reinterpret_cast<const uint4*>(vp + 8);
    }

    for (int kt = 0; kt < 32; ++kt) {
        __syncthreads();
        *reinterpret_cast<uint4*>(&Ks[sr][sc])     = kr0;
        *reinterpret_cast<uint4*>(&Ks[sr][sc + 8]) = kr1;
        *reinterpret_cast<uint4*>(&Vs[sr][sc])     = vr0;
        *reinterpret_cast<uint4*>(&Vs[sr][sc + 8]) = vr1;
        __syncthreads();
        if (kt + 1 < 32) {
            const int kn = (kt + 1) * 64;
            const unsigned short* kp = Kg + (size_t)(kn + sr) * C_ + h * D_ + sc;
            kr0 = *reinterpret_cast<const uint4*>(kp);
            kr1 = *reinterpret_cast<const uint4*>(kp + 8);
            const unsigned short* vp = Vg + (size_t)sr * L_ + kn + sc;
            vr0 = *reinterpret_cast<const uint4*>(vp);
            vr1 = *reinterpret_cast<const uint4*>(vp + 8);
        }

        // ---- S^T = K Q^T : sacc[f][r] = S[k=16f+4g+r][q=q16] ----
        f32x4 sacc[4];
        #pragma unroll
        for (int f = 0; f < 4; ++f) sacc[f] = zero4;
        #pragma unroll
        for (int s = 0; s < 2; ++s) {
            #pragma unroll
            for (int f = 0; f < 4; ++f) {
                bf16x8 kf = frag_ld(&Ks[16 * f + q16][32 * s + 8 * g]);
                sacc[f] = __builtin_amdgcn_mfma_f32_16x16x32_bf16(
                    kf, qf[s], sacc[f], 0, 0, 0);
            }
        }

        // ---- tile max over 16 in-lane values (v_max3 tree) + 2 shfl ----
        const float t0 = fmax3(sacc[0][0], sacc[0][1], sacc[0][2]);
        const float t1 = fmax3(sacc[0][3], sacc[1][0], sacc[1][1]);
        const float t2 = fmax3(sacc[1][2], sacc[1][3], sacc[2][0]);
        const float t3 = fmax3(sacc[2][1], sacc[2][2], sacc[2][3]);
        const float t4 = fmax3(sacc[3][0], sacc[3][1], sacc[3][2]);
        float pm = fmaxf(fmax3(t0, t1, t2), fmax3(t3, t4, sacc[3][3]));
        pm = fmaxf(pm, __shfl_xor(pm, 16));
        pm = fmaxf(pm, __shfl_xor(pm, 32));

        // ---- defer-max rescale ----
        if (!__all(pm - m_s <= DEFER_THR)) {
            const float mn   = fmaxf(m_s, pm);
            const float corr = exp2f(m_s - mn);
            m_s = mn;
            l_p *= corr;
            #pragma unroll
            for (int r = 0; r < 4; ++r) {
                const float c_o = __shfl(corr, 20 * g + r);
                #pragma unroll
                for (int n = 0; n < 4; ++n) oacc[n][r] *= c_o;
            }
        }

        // ---- exp2 + per-lane partial sum ----
        float p[4][4];
        #pragma unroll
        for (int f = 0; f < 4; ++f) {
            #pragma unroll
            for (int r = 0; r < 4; ++r) p[f][r] = exp2f(sacc[f][r] - m_s);
            l_p += (p[f][0] + p[f][1]) + (p[f][2] + p[f][3]);
        }

        // ---- P store: hw pack + XOR-swizzled uint2 (conflict-free) ----
        #pragma unroll
        for (int f = 0; f < 4; ++f) {
            uint2 v2;
            v2.x = cvt_pk(p[f][0], p[f][1]);
            v2.y = cvt_pk(p[f][2], p[f][3]);
            *reinterpret_cast<uint2*>(pw + ((8 * f + 2 * g) ^ h4)) = v2;
        }

        // ---- O += P V (wave-private P, swizzled read, no barrier) ----
        #pragma unroll
        for (int s2 = 0; s2 < 2; ++s2) {
            bf16x8 pf = frag_ld(reinterpret_cast<const unsigned short*>(
                pw + ((16 * s2 + 4 * g) ^ h4)));
            #pragma unroll
            for (int n = 0; n < 4; ++n) {
                bf16x8 vf = frag_ld(&Vs[16 * n + q16][32 * s2 + 8 * g]);
                oacc[n] = __builtin_amdgcn_mfma_f32_16x16x32_bf16(
                    pf, vf, oacc[n], 0, 0, 0);
            }
        }
    }

    // ---- epilogue: reduce l across the 4 dup lanes, normalize, store ----
    float lr = l_p;
    lr += __shfl_xor(lr, 16);
    lr += __shfl_xor(lr, 32);
    #pragma unroll
    for (int r = 0; r < 4; ++r) {
        const float l_o = __shfl(lr, 20 * g + r);
        const float inv = 1.f / l_o;
        const int q = q0 + 16 * wid + 4 * g + r;
        #pragma unroll
        for (int n = 0; n < 4; ++n)
            Ag[(size_t)q * C_ + h * D_ + 16 * n + q16] = f2bf_hw(oacc[n][r] * inv);
    }
}

// =====================================================================
extern "C" void kernel_launch(void* const* d_in, const int* in_sizes, int n_in,
                              void* d_out, int out_size, void* d_ws, size_t ws_size,
                              hipStream_t stream)
{
    const float* x  = (const float*)d_in[0];
    const float* Wq = (const float*)d_in[1];
    const float* bq = (const float*)d_in[2];
    const float* Wk = (const float*)d_in[3];
    const float* bk = (const float*)d_in[4];
    const float* Wv = (const float*)d_in[5];
    const float* bv = (const float*)d_in[6];
    const float* Wo = (const float*)d_in[7];
    const float* bo = (const float*)d_in[8];
    float* out = (float*)d_out;

    const size_t NB = (size_t)B_ * L_ * C_;
    const size_t NW = (size_t)C_ * C_;
    unsigned short* ws16 = (unsigned short*)d_ws;
    unsigned short* xt  = ws16;
    unsigned short* qb  = xt  + NB;
    unsigned short* kb  = qb  + NB;
    unsigned short* vb  = kb  + NB;
    unsigned short* att = vb  + NB;
    unsigned short* wqb = att + NB;
    unsigned short* wkb = wqb + NW;
    unsigned short* wvb = wkb + NW;
    unsigned short* wob = wvb + NW;

    prep<<<dim3(32, 8, 2 * B_), 256, 0, stream>>>(
        x, Wq, Wk, Wv, Wo, xt, wqb, wkb, wvb, wob);

    qkv_gemm<<<dim3(4, 16, 3 * B_), 256, 0, stream>>>(
        xt, wqb, wkb, wvb, bq, bk, bv, qb, kb, vb);

    attn_mfma<<<dim3(L_ / 64, H_, B_), 256, 0, stream>>>(qb, kb, vb, att);

    gemm_out<<<dim3(16, 4, B_), 256, 0, stream>>>(wob, att, bo, out, x);
}